// Round 1
// baseline (147.372 us; speedup 1.0000x reference)
//
#include <hip/hip_runtime.h>
#include <math.h>

typedef __attribute__((ext_vector_type(4))) float f32x4;
typedef __attribute__((ext_vector_type(4))) unsigned int u32x4;
typedef __attribute__((ext_vector_type(8))) short s16x8;

#define SCALE_INV_SQRT_H 0.08838834764831845f  /* 1/sqrt(128) */

__device__ __forceinline__ unsigned short f2bf(float x){
  unsigned int u = __builtin_bit_cast(unsigned int, x);
  u += 0x7fffu + ((u >> 16) & 1u);
  return (unsigned short)(u >> 16);
}
__device__ __forceinline__ float bf2f(unsigned short s){
  unsigned int u = ((unsigned int)s) << 16;
  return __builtin_bit_cast(float, u);
}

// ---------------- shared 128x128-tile NT GEMM core (A,B both K-contiguous bf16) ---------
// 256 threads = 4 waves (2x2 of 64x64), 16x16x32 bf16 MFMA, BK=64, swizzled LDS.
__device__ __forceinline__ void gemm_core(
    const unsigned short* __restrict__ Ag, int lda,
    const unsigned short* __restrict__ Bg, int ldb,
    int ksteps, unsigned short* As, unsigned short* Bs, f32x4 acc[4][4])
{
  const int t = threadIdx.x, lane = t & 63, w = t >> 6;
  const int m0 = (w >> 1) * 64, n0 = (w & 1) * 64;
  const int r = t >> 1, u0 = (t & 1) * 4;
  for (int kk = 0; kk < ksteps; kk++) {
    __syncthreads();
    const unsigned short* ga = Ag + (size_t)r * lda + kk * 64;
    const unsigned short* gb = Bg + (size_t)r * ldb + kk * 64;
#pragma unroll
    for (int q = 0; q < 4; q++) {
      u32x4 va = *(const u32x4*)(ga + (u0 + q) * 8);
      u32x4 vb = *(const u32x4*)(gb + (u0 + q) * 8);
      ((u32x4*)(As + r * 64))[(u0 + q) ^ (r & 7)] = va;
      ((u32x4*)(Bs + r * 64))[(u0 + q) ^ (r & 7)] = vb;
    }
    __syncthreads();
    s16x8 af[4][2], bfr[4][2];
#pragma unroll
    for (int i = 0; i < 4; i++) {
#pragma unroll
      for (int ks = 0; ks < 2; ks++) {
        int ra = m0 + i * 16 + (lane & 15);
        int sa = ks * 4 + (lane >> 4);
        af[i][ks] = *(const s16x8*)(As + ra * 64 + ((sa ^ (ra & 7)) << 3));
        int rb = n0 + i * 16 + (lane & 15);
        bfr[i][ks] = *(const s16x8*)(Bs + rb * 64 + ((sa ^ (rb & 7)) << 3));
      }
    }
#pragma unroll
    for (int ks = 0; ks < 2; ks++)
#pragma unroll
      for (int i = 0; i < 4; i++)
#pragma unroll
        for (int j = 0; j < 4; j++)
          acc[i][j] = __builtin_amdgcn_mfma_f32_16x16x32_bf16(af[i][ks], bfr[j][ks], acc[i][j], 0, 0, 0);
  }
}

__device__ __forceinline__ void store_bf16_tile(unsigned short* __restrict__ C, int ldc, f32x4 acc[4][4]){
  const int t = threadIdx.x, lane = t & 63, w = t >> 6;
  const int m0 = (w >> 1) * 64, n0 = (w & 1) * 64;
#pragma unroll
  for (int i = 0; i < 4; i++)
#pragma unroll
    for (int j = 0; j < 4; j++) {
      int col = n0 + j * 16 + (lane & 15);
#pragma unroll
      for (int rg = 0; rg < 4; rg++) {
        int row = m0 + i * 16 + (lane >> 4) * 4 + rg;
        C[(size_t)row * ldc + col] = f2bf(acc[i][j][rg]);
      }
    }
}

// ---------------- K0: convert/transpose weights + me to bf16 -----------------------------
__global__ __launch_bounds__(256) void k_conv(
  const float* __restrict__ me, const float* __restrict__ Wq, const float* __restrict__ Wk,
  const float* __restrict__ Wv, const float* __restrict__ Wo,
  unsigned short* __restrict__ me_b, unsigned short* __restrict__ wq_b, unsigned short* __restrict__ wk_b,
  unsigned short* __restrict__ wvt_b, unsigned short* __restrict__ wot_b)
{
  const int ME_N = 2048 * 512;
  const int W_N  = 8 * 512 * 128;
  const int WO_N = 1024 * 512;
  const int tot = ME_N + 3 * W_N + WO_N;
  for (int e = blockIdx.x * 256 + threadIdx.x; e < tot; e += gridDim.x * 256) {
    if (e < ME_N) { me_b[e] = f2bf(me[e]); }
    else if (e < ME_N + W_N) { int i = e - ME_N; wq_b[i] = f2bf(Wq[i]); }
    else if (e < ME_N + 2 * W_N) { int i = e - ME_N - W_N; wk_b[i] = f2bf(Wk[i]); }
    else if (e < ME_N + 3 * W_N) {
      int i = e - ME_N - 2 * W_N;
      int h = i >> 16, rem = i & 65535, d = rem >> 9, k = rem & 511;
      wvt_b[i] = f2bf(Wv[h * 65536 + k * 128 + d]);      // wvt[h][d][k]
    } else {
      int i = e - ME_N - 3 * W_N;
      int j = i >> 10, k = i & 1023;
      wot_b[i] = f2bf(Wo[k * 512 + j]);                  // wot[j][k]
    }
  }
}

// ---------------- K0b: r[h*512+j] = sum_d Wk[h][j][d]*bq[h][d] ---------------------------
__global__ __launch_bounds__(256) void k_r(const float* __restrict__ Wk, const float* __restrict__ bq,
                                           float* __restrict__ rbuf)
{
  int g = blockIdx.x * 256 + threadIdx.x;   // 0..4095
  int h = g >> 9, j = g & 511;
  float s = 0.f;
  for (int d = 0; d < 128; d++) s += Wk[h * 65536 + j * 128 + d] * bq[h * 128 + d];
  rbuf[g] = s;
}

// ---------------- K1: Mt[h*512+j][i] = sum_d Wk[h][j][d]*Wq[h][i][d] ---------------------
__global__ __launch_bounds__(256) void k_mt(const unsigned short* __restrict__ wk_b,
                                            const unsigned short* __restrict__ wq_b,
                                            unsigned short* __restrict__ mt)
{
  __shared__ unsigned short As[128 * 64], Bs[128 * 64];
  int bid = blockIdx.x;
  int h = bid >> 4, tm = (bid >> 2) & 3, tn = bid & 3;
  f32x4 acc[4][4]; f32x4 z = {0.f, 0.f, 0.f, 0.f};
#pragma unroll
  for (int i = 0; i < 4; i++) for (int j = 0; j < 4; j++) acc[i][j] = z;
  gemm_core(wk_b + h * 65536 + tm * 16384, 128, wq_b + h * 65536 + tn * 16384, 128, 2, As, Bs, acc);
  store_bf16_tile(mt + (size_t)(h * 512 + tm * 128) * 512 + tn * 128, 512, acc);
}

// ---------------- K2: T[b][c] = (sum_i me[b][i]*Mt[c][i] + r[c]) * scale  (bf16) ---------
__global__ __launch_bounds__(256) void k_t(const unsigned short* __restrict__ me_b,
                                           const unsigned short* __restrict__ mt,
                                           const float* __restrict__ rbuf,
                                           unsigned short* __restrict__ T)
{
  __shared__ unsigned short As[128 * 64], Bs[128 * 64];
  int bid = blockIdx.x;
  int bm = bid >> 5, bn = bid & 31;
  f32x4 acc[4][4]; f32x4 z = {0.f, 0.f, 0.f, 0.f};
#pragma unroll
  for (int i = 0; i < 4; i++) for (int j = 0; j < 4; j++) acc[i][j] = z;
  gemm_core(me_b + (size_t)bm * 128 * 512, 512, mt + (size_t)bn * 128 * 512, 512, 8, As, Bs, acc);
  const int t = threadIdx.x, lane = t & 63, w = t >> 6;
  const int m0 = (w >> 1) * 64, n0 = (w & 1) * 64;
#pragma unroll
  for (int i = 0; i < 4; i++)
#pragma unroll
    for (int j = 0; j < 4; j++) {
      int col = bn * 128 + n0 + j * 16 + (lane & 15);
      float rv = rbuf[col];
#pragma unroll
      for (int rg = 0; rg < 4; rg++) {
        int row = bm * 128 + m0 + i * 16 + (lane >> 4) * 4 + rg;
        T[(size_t)row * 4096 + col] = f2bf((acc[i][j][rg] + rv) * SCALE_INV_SQRT_H);
      }
    }
}

// ---------------- K3: fused per-batch attention (scores -> softmax -> w = a@other) -------
__global__ __launch_bounds__(256) void k_attn(const float* __restrict__ other,
                                              const unsigned short* __restrict__ T,
                                              unsigned short* __restrict__ wbuf)
{
  __shared__ unsigned short oth_rm[64 * 512];   // [n][k] bf16, swizzled
  __shared__ unsigned short oth_cm[512 * 64];   // [k][n] bf16, swizzled
  __shared__ unsigned short t_lds[16 * 512];    // [h][k] bf16 (rows 8..15 unused garbage)
  __shared__ unsigned short a_lds[16 * 64];     // [h][n] bf16 probs (rows 8..15 zero)
  __shared__ float s_lds[8 * 66];               // [h][n] fp32 scores, padded
  const int b = blockIdx.x;
  const int t = threadIdx.x, lane = t & 63, w = t >> 6;

  // stage T rows (8 heads x 512)
  {
    int h = t >> 5;
    const unsigned short* g = T + (size_t)b * 4096 + h * 512;
#pragma unroll
    for (int i = 0; i < 2; i++) {
      int u = (t & 31) * 2 + i;
      u32x4 v = *(const u32x4*)(g + u * 8);
      ((u32x4*)(t_lds + h * 512))[u ^ (h & 15)] = v;
    }
  }
  // stage other: fp32 -> bf16, dual layout, pipelined loads
  {
    int n = t >> 2;
    const f32x4* g = (const f32x4*)(other + (size_t)b * 32768 + (size_t)n * 512);
#pragma unroll
    for (int i0 = 0; i0 < 32; i0 += 8) {
      f32x4 v[8];
#pragma unroll
      for (int jj = 0; jj < 8; jj++) v[jj] = g[(t & 3) + (i0 + jj) * 4];
#pragma unroll
      for (int jj = 0; jj < 8; jj++) {
        int k = (t & 3) * 4 + (i0 + jj) * 16;
        unsigned short b0 = f2bf(v[jj][0]), b1 = f2bf(v[jj][1]);
        unsigned short b2 = f2bf(v[jj][2]), b3 = f2bf(v[jj][3]);
        unsigned long long pk = (unsigned long long)((unsigned)b0 | ((unsigned)b1 << 16))
                              | (((unsigned long long)((unsigned)b2 | ((unsigned)b3 << 16))) << 32);
        *(unsigned long long*)((char*)oth_rm + n * 1024 + ((k * 2) ^ ((n & 15) << 4))) = pk;
        unsigned short bb[4] = {b0, b1, b2, b3};
#pragma unroll
        for (int q = 0; q < 4; q++) {
          int kq = k + q;
          *(unsigned short*)((char*)oth_cm + kq * 128 + ((n * 2) ^ ((kq & 7) << 4))) = bb[q];
        }
      }
    }
  }
  __syncthreads();

  // GEMM1: S[n][h] = sum_k other[n][k] * T[h][k]  (wave w owns n in [16w,16w+16))
  f32x4 sacc = {0.f, 0.f, 0.f, 0.f};
  {
    int arow = w * 16 + (lane & 15);
    int brow = lane & 15;
#pragma unroll
    for (int ks = 0; ks < 16; ks++) {
      int slot = ks * 4 + (lane >> 4);
      s16x8 af  = *(const s16x8*)(oth_rm + arow * 512 + ((slot ^ (arow & 15)) << 3));
      s16x8 bfv = *(const s16x8*)(t_lds + brow * 512 + ((slot ^ (brow & 15)) << 3));
      sacc = __builtin_amdgcn_mfma_f32_16x16x32_bf16(af, bfv, sacc, 0, 0, 0);
    }
    int h = lane & 15;
    if (h < 8) {
#pragma unroll
      for (int rg = 0; rg < 4; rg++) {
        int n = w * 16 + (lane >> 4) * 4 + rg;
        s_lds[h * 66 + n] = sacc[rg];
      }
    }
  }
  __syncthreads();

  // softmax over n=64 per head; wave w handles heads 2w,2w+1
#pragma unroll
  for (int hh = 0; hh < 2; hh++) {
    int h = w * 2 + hh;
    float v = s_lds[h * 66 + lane];
    float mx = v;
#pragma unroll
    for (int off = 32; off > 0; off >>= 1) mx = fmaxf(mx, __shfl_xor(mx, off));
    float p = __expf(v - mx);
    float sm = p;
#pragma unroll
    for (int off = 32; off > 0; off >>= 1) sm += __shfl_xor(sm, off);
    unsigned short a = f2bf(p / sm);
    *(unsigned short*)((char*)a_lds + h * 128 + ((lane * 2) ^ ((h & 7) << 4))) = a;
    int h2 = h + 8;
    *(unsigned short*)((char*)a_lds + h2 * 128 + ((lane * 2) ^ ((h2 & 7) << 4))) = 0;
  }
  __syncthreads();

  // GEMM2: w[h][k] = sum_n a[h][n]*other[n][k]  (wave w owns k in [128w,128w+128))
  {
    f32x4 wacc[8]; f32x4 z = {0.f, 0.f, 0.f, 0.f};
#pragma unroll
    for (int i = 0; i < 8; i++) wacc[i] = z;
    int arow = lane & 15;
#pragma unroll
    for (int ks = 0; ks < 2; ks++) {
      int slot = ks * 4 + (lane >> 4);
      s16x8 af = *(const s16x8*)(a_lds + arow * 64 + ((slot ^ (arow & 7)) << 3));
#pragma unroll
      for (int nf = 0; nf < 8; nf++) {
        int brow = w * 128 + nf * 16 + (lane & 15);
        s16x8 bfv = *(const s16x8*)(oth_cm + brow * 64 + ((slot ^ (brow & 7)) << 3));
        wacc[nf] = __builtin_amdgcn_mfma_f32_16x16x32_bf16(af, bfv, wacc[nf], 0, 0, 0);
      }
    }
    if (lane < 32) {
#pragma unroll
      for (int nf = 0; nf < 8; nf++) {
        int k = w * 128 + nf * 16 + (lane & 15);
#pragma unroll
        for (int rg = 0; rg < 4; rg++) {
          int h = (lane >> 4) * 4 + rg;
          wbuf[((size_t)b * 8 + h) * 512 + k] = f2bf(wacc[nf][rg]);
        }
      }
    }
  }
}

// ---------------- K4: c[b][h*128+d] = sum_k w[b][h][k]*Wv[h][k][d]  (bf16) ---------------
__global__ __launch_bounds__(256) void k_c(const unsigned short* __restrict__ wbuf,
                                           const unsigned short* __restrict__ wvt,
                                           unsigned short* __restrict__ cbuf)
{
  __shared__ unsigned short As[128 * 64], Bs[128 * 64];
  int bid = blockIdx.x;
  int bm = bid >> 3, h = bid & 7;
  f32x4 acc[4][4]; f32x4 z = {0.f, 0.f, 0.f, 0.f};
#pragma unroll
  for (int i = 0; i < 4; i++) for (int j = 0; j < 4; j++) acc[i][j] = z;
  gemm_core(wbuf + ((size_t)bm * 128 * 8 + h) * 512, 4096, wvt + h * 65536, 512, 8, As, Bs, acc);
  store_bf16_tile(cbuf + (size_t)bm * 128 * 1024 + h * 128, 1024, acc);
}

// ---------------- K5: LN + ReLU + out = cn @ Wo  (fp32 out) ------------------------------
__global__ __launch_bounds__(256) void k_out(const unsigned short* __restrict__ cbuf,
                                             const float* __restrict__ gamma,
                                             const float* __restrict__ beta,
                                             const unsigned short* __restrict__ wot,
                                             float* __restrict__ out)
{
  __shared__ unsigned short As[32 * 1024];   // c tile (full K), swizzled
  __shared__ unsigned short Bs[128 * 64];
  int bid = blockIdx.x;
  int bm = bid >> 2, bn = bid & 3;
  const int t = threadIdx.x, lane = t & 63, w = t >> 6;
  // stage c rows
  {
    int r = t >> 3;
    const unsigned short* g = cbuf + (size_t)(bm * 32 + r) * 1024;
#pragma unroll
    for (int q = 0; q < 16; q++) {
      int u = (t & 7) + q * 8;
      u32x4 v = *(const u32x4*)(g + u * 8);
      ((u32x4*)(As + r * 1024))[u ^ (r & 7)] = v;
    }
  }
  // gamma/beta for this lane's fixed k positions
  float gv[16], bv[16];
#pragma unroll
  for (int si = 0; si < 2; si++)
#pragma unroll
    for (int j = 0; j < 8; j++) {
      int k = (lane + si * 64) * 8 + j;
      gv[si * 8 + j] = gamma[k];
      bv[si * 8 + j] = beta[k];
    }
  __syncthreads();
  // LayerNorm + ReLU in LDS (wave w owns rows [8w, 8w+8))
  for (int rr = 0; rr < 8; rr++) {
    int r = w * 8 + rr;
    float vals[16]; float sum = 0.f, sq = 0.f;
#pragma unroll
    for (int si = 0; si < 2; si++) {
      int s = lane + si * 64;
      s16x8 pv = *(const s16x8*)(As + r * 1024 + ((s ^ (r & 7)) << 3));
#pragma unroll
      for (int j = 0; j < 8; j++) { float f = bf2f((unsigned short)pv[j]); vals[si * 8 + j] = f; sum += f; sq += f * f; }
    }
#pragma unroll
    for (int off = 32; off > 0; off >>= 1) { sum += __shfl_xor(sum, off); sq += __shfl_xor(sq, off); }
    float mu = sum * (1.f / 1024.f);
    float var = sq * (1.f / 1024.f) - mu * mu;
    float rs = rsqrtf(var + 1e-5f);
#pragma unroll
    for (int si = 0; si < 2; si++) {
      int s = lane + si * 64;
      unsigned short o[8];
#pragma unroll
      for (int j = 0; j < 8; j++) {
        float f = (vals[si * 8 + j] - mu) * rs * gv[si * 8 + j] + bv[si * 8 + j];
        o[j] = f2bf(fmaxf(f, 0.f));
      }
      u32x4 pk;
      pk[0] = (unsigned)o[0] | ((unsigned)o[1] << 16);
      pk[1] = (unsigned)o[2] | ((unsigned)o[3] << 16);
      pk[2] = (unsigned)o[4] | ((unsigned)o[5] << 16);
      pk[3] = (unsigned)o[6] | ((unsigned)o[7] << 16);
      ((u32x4*)(As + r * 1024))[s ^ (r & 7)] = pk;
    }
  }
  // GEMM: out_tile[32x128] = cn_tile @ Wo_t(bn)
  const int wm = w >> 1, wn = w & 1;
  f32x4 acc[4]; f32x4 z = {0.f, 0.f, 0.f, 0.f};
#pragma unroll
  for (int j = 0; j < 4; j++) acc[j] = z;
  const unsigned short* Bg = wot + (size_t)bn * 128 * 1024;
  const int rB = t >> 1, u0 = (t & 1) * 4;
  for (int kk = 0; kk < 16; kk++) {
    __syncthreads();
#pragma unroll
    for (int q = 0; q < 4; q++) {
      u32x4 vb = *(const u32x4*)(Bg + (size_t)rB * 1024 + kk * 64 + (u0 + q) * 8);
      ((u32x4*)(Bs + rB * 64))[(u0 + q) ^ (rB & 7)] = vb;
    }
    __syncthreads();
#pragma unroll
    for (int ks = 0; ks < 2; ks++) {
      int ra = wm * 16 + (lane & 15);
      int sa = kk * 8 + ks * 4 + (lane >> 4);
      s16x8 af = *(const s16x8*)(As + ra * 1024 + ((sa ^ (ra & 7)) << 3));
#pragma unroll
      for (int j = 0; j < 4; j++) {
        int rb = wn * 64 + j * 16 + (lane & 15);
        int sb = ks * 4 + (lane >> 4);
        s16x8 bfv = *(const s16x8*)(Bs + rb * 64 + ((sb ^ (rb & 7)) << 3));
        acc[j] = __builtin_amdgcn_mfma_f32_16x16x32_bf16(af, bfv, acc[j], 0, 0, 0);
      }
    }
  }
#pragma unroll
  for (int j = 0; j < 4; j++) {
    int col = bn * 128 + wn * 64 + j * 16 + (lane & 15);
#pragma unroll
    for (int rg = 0; rg < 4; rg++) {
      int row = bm * 32 + wm * 16 + (lane >> 4) * 4 + rg;
      out[(size_t)row * 512 + col] = acc[j][rg];
    }
  }
}

// -----------------------------------------------------------------------------------------
extern "C" void kernel_launch(void* const* d_in, const int* in_sizes, int n_in,
                              void* d_out, int out_size, void* d_ws, size_t ws_size,
                              hipStream_t stream)
{
  (void)in_sizes; (void)n_in; (void)out_size;
  const float* me    = (const float*)d_in[0];
  const float* other = (const float*)d_in[1];
  const float* Wq    = (const float*)d_in[2];
  const float* bq    = (const float*)d_in[3];
  const float* Wk    = (const float*)d_in[4];
  const float* Wv    = (const float*)d_in[5];
  const float* gamma = (const float*)d_in[6];
  const float* beta  = (const float*)d_in[7];
  const float* Wo    = (const float*)d_in[8];
  float* out = (float*)d_out;
  char* ws = (char*)d_ws;

  // workspace layout (bytes)
  unsigned short* me_b  = (unsigned short*)(ws + 0);          //  2 MB me bf16
  unsigned short* wq_b  = (unsigned short*)(ws + 2097152);    //  1 MB
  unsigned short* wk_b  = (unsigned short*)(ws + 3145728);    //  1 MB
  unsigned short* wvt_b = (unsigned short*)(ws + 4194304);    //  1 MB  Wv^T per head
  unsigned short* wot_b = (unsigned short*)(ws + 5242880);    //  1 MB  Wo^T
  float*          rbuf  = (float*)(ws + 6291456);             // 16 KB  Wk@bq
  unsigned short* mt_b  = (unsigned short*)(ws + 6307840);    //  4 MB  WqWk^T stacked
  unsigned short* T_b   = (unsigned short*)(ws + 10502144);   // 16 MB  T = me@M
  unsigned short* w_b   = (unsigned short*)(ws + 27279360);   // 16 MB  w = a@other
  unsigned short* c_b   = (unsigned short*)(ws + 44056576);   //  4 MB  c = w@Wv
  if (ws_size < 48250880) return;  // visible failure instead of corruption

  k_conv<<<dim3(1024), dim3(256), 0, stream>>>(me, Wq, Wk, Wv, Wo, me_b, wq_b, wk_b, wvt_b, wot_b);
  k_r   <<<dim3(16),   dim3(256), 0, stream>>>(Wk, bq, rbuf);
  k_mt  <<<dim3(128),  dim3(256), 0, stream>>>(wk_b, wq_b, mt_b);
  k_t   <<<dim3(512),  dim3(256), 0, stream>>>(me_b, mt_b, rbuf, T_b);
  k_attn<<<dim3(2048), dim3(256), 0, stream>>>(other, T_b, w_b);
  k_c   <<<dim3(128),  dim3(256), 0, stream>>>(w_b, wvt_b, c_b);
  k_out <<<dim3(256),  dim3(256), 0, stream>>>(c_b, gamma, beta, wot_b, out);
}

// Round 2
// 136.768 us; speedup vs baseline: 1.0775x; 1.0775x over previous
//
#include <hip/hip_runtime.h>
#include <math.h>

typedef __attribute__((ext_vector_type(4))) float f32x4;
typedef __attribute__((ext_vector_type(4))) unsigned int u32x4;
typedef __attribute__((ext_vector_type(8))) short s16x8;

#define SCALE_INV_SQRT_H 0.08838834764831845f  /* 1/sqrt(128) */

__device__ __forceinline__ unsigned short f2bf(float x){
  unsigned int u = __builtin_bit_cast(unsigned int, x);
  u += 0x7fffu + ((u >> 16) & 1u);
  return (unsigned short)(u >> 16);
}
__device__ __forceinline__ float bf2f(unsigned short s){
  unsigned int u = ((unsigned int)s) << 16;
  return __builtin_bit_cast(float, u);
}

// ---------------- shared 128x128-tile NT GEMM core (A,B both K-contiguous bf16) ---------
__device__ __forceinline__ void gemm_core(
    const unsigned short* __restrict__ Ag, int lda,
    const unsigned short* __restrict__ Bg, int ldb,
    int ksteps, unsigned short* As, unsigned short* Bs, f32x4 acc[4][4])
{
  const int t = threadIdx.x, lane = t & 63, w = t >> 6;
  const int m0 = (w >> 1) * 64, n0 = (w & 1) * 64;
  const int r = t >> 1, u0 = (t & 1) * 4;
  for (int kk = 0; kk < ksteps; kk++) {
    __syncthreads();
    const unsigned short* ga = Ag + (size_t)r * lda + kk * 64;
    const unsigned short* gb = Bg + (size_t)r * ldb + kk * 64;
#pragma unroll
    for (int q = 0; q < 4; q++) {
      u32x4 va = *(const u32x4*)(ga + (u0 + q) * 8);
      u32x4 vb = *(const u32x4*)(gb + (u0 + q) * 8);
      ((u32x4*)(As + r * 64))[(u0 + q) ^ (r & 7)] = va;
      ((u32x4*)(Bs + r * 64))[(u0 + q) ^ (r & 7)] = vb;
    }
    __syncthreads();
    s16x8 af[4][2], bfr[4][2];
#pragma unroll
    for (int i = 0; i < 4; i++) {
#pragma unroll
      for (int ks = 0; ks < 2; ks++) {
        int ra = m0 + i * 16 + (lane & 15);
        int sa = ks * 4 + (lane >> 4);
        af[i][ks] = *(const s16x8*)(As + ra * 64 + ((sa ^ (ra & 7)) << 3));
        int rb = n0 + i * 16 + (lane & 15);
        bfr[i][ks] = *(const s16x8*)(Bs + rb * 64 + ((sa ^ (rb & 7)) << 3));
      }
    }
#pragma unroll
    for (int ks = 0; ks < 2; ks++)
#pragma unroll
      for (int i = 0; i < 4; i++)
#pragma unroll
        for (int j = 0; j < 4; j++)
          acc[i][j] = __builtin_amdgcn_mfma_f32_16x16x32_bf16(af[i][ks], bfr[j][ks], acc[i][j], 0, 0, 0);
  }
}

__device__ __forceinline__ void store_bf16_tile(unsigned short* __restrict__ C, int ldc, f32x4 acc[4][4]){
  const int t = threadIdx.x, lane = t & 63, w = t >> 6;
  const int m0 = (w >> 1) * 64, n0 = (w & 1) * 64;
#pragma unroll
  for (int i = 0; i < 4; i++)
#pragma unroll
    for (int j = 0; j < 4; j++) {
      int col = n0 + j * 16 + (lane & 15);
#pragma unroll
      for (int rg = 0; rg < 4; rg++) {
        int row = m0 + i * 16 + (lane >> 4) * 4 + rg;
        C[(size_t)row * ldc + col] = f2bf(acc[i][j][rg]);
      }
    }
}

// ---------------- K0: convert/transpose weights + me to bf16; blocks>=1024 do r=Wk@bq ---
__global__ __launch_bounds__(256) void k_conv(
  const float* __restrict__ me, const float* __restrict__ Wq, const float* __restrict__ Wk,
  const float* __restrict__ Wv, const float* __restrict__ Wo, const float* __restrict__ bq,
  unsigned short* __restrict__ me_b, unsigned short* __restrict__ wq_b, unsigned short* __restrict__ wk_b,
  unsigned short* __restrict__ wvt_b, unsigned short* __restrict__ wot_b, float* __restrict__ rbuf)
{
  if (blockIdx.x >= 1024) {   // k_r part: r[h*512+j] = sum_d Wk[h][j][d]*bq[h][d]
    int g = (blockIdx.x - 1024) * 256 + threadIdx.x;   // 0..4095
    int h = g >> 9, j = g & 511;
    float s = 0.f;
    for (int d = 0; d < 128; d++) s += Wk[h * 65536 + j * 128 + d] * bq[h * 128 + d];
    rbuf[g] = s;
    return;
  }
  const int ME_N = 2048 * 512;
  const int W_N  = 8 * 512 * 128;
  const int WO_N = 1024 * 512;
  const int tot = ME_N + 3 * W_N + WO_N;
  for (int e = blockIdx.x * 256 + threadIdx.x; e < tot; e += 1024 * 256) {
    if (e < ME_N) { me_b[e] = f2bf(me[e]); }
    else if (e < ME_N + W_N) { int i = e - ME_N; wq_b[i] = f2bf(Wq[i]); }
    else if (e < ME_N + 2 * W_N) { int i = e - ME_N - W_N; wk_b[i] = f2bf(Wk[i]); }
    else if (e < ME_N + 3 * W_N) {
      int i = e - ME_N - 2 * W_N;
      int h = i >> 16, rem = i & 65535, d = rem >> 9, k = rem & 511;
      wvt_b[i] = f2bf(Wv[h * 65536 + k * 128 + d]);      // wvt[h][d][k]
    } else {
      int i = e - ME_N - 3 * W_N;
      int j = i >> 10, k = i & 1023;
      wot_b[i] = f2bf(Wo[k * 512 + j]);                  // wot[j][k]
    }
  }
}

// ---------------- K1: Mt[h*512+j][i] = sum_d Wk[h][j][d]*Wq[h][i][d] ---------------------
__global__ __launch_bounds__(256) void k_mt(const unsigned short* __restrict__ wk_b,
                                            const unsigned short* __restrict__ wq_b,
                                            unsigned short* __restrict__ mt)
{
  __shared__ unsigned short As[128 * 64], Bs[128 * 64];
  int bid = blockIdx.x;
  int h = bid >> 4, tm = (bid >> 2) & 3, tn = bid & 3;
  f32x4 acc[4][4]; f32x4 z = {0.f, 0.f, 0.f, 0.f};
#pragma unroll
  for (int i = 0; i < 4; i++) for (int j = 0; j < 4; j++) acc[i][j] = z;
  gemm_core(wk_b + h * 65536 + tm * 16384, 128, wq_b + h * 65536 + tn * 16384, 128, 2, As, Bs, acc);
  store_bf16_tile(mt + (size_t)(h * 512 + tm * 128) * 512 + tn * 128, 512, acc);
}

// ---------------- K2: T[b][c] = (sum_i me[b][i]*Mt[c][i] + r[c]) * scale  (bf16) ---------
__global__ __launch_bounds__(256) void k_t(const unsigned short* __restrict__ me_b,
                                           const unsigned short* __restrict__ mt,
                                           const float* __restrict__ rbuf,
                                           unsigned short* __restrict__ T)
{
  __shared__ unsigned short As[128 * 64], Bs[128 * 64];
  // XCD-aware swizzle (512 = 8*64, bijective): each XCD keeps 2 A-panels resident in L2
  int bid = blockIdx.x;
  int swz = (bid & 7) * 64 + (bid >> 3);
  int bm = swz >> 5, bn = swz & 31;
  f32x4 acc[4][4]; f32x4 z = {0.f, 0.f, 0.f, 0.f};
#pragma unroll
  for (int i = 0; i < 4; i++) for (int j = 0; j < 4; j++) acc[i][j] = z;
  gemm_core(me_b + (size_t)bm * 128 * 512, 512, mt + (size_t)bn * 128 * 512, 512, 8, As, Bs, acc);
  const int t = threadIdx.x, lane = t & 63, w = t >> 6;
  const int m0 = (w >> 1) * 64, n0 = (w & 1) * 64;
#pragma unroll
  for (int i = 0; i < 4; i++)
#pragma unroll
    for (int j = 0; j < 4; j++) {
      int col = bn * 128 + n0 + j * 16 + (lane & 15);
      float rv = rbuf[col];
#pragma unroll
      for (int rg = 0; rg < 4; rg++) {
        int row = bm * 128 + m0 + i * 16 + (lane >> 4) * 4 + rg;
        T[(size_t)row * 4096 + col] = f2bf((acc[i][j][rg] + rv) * SCALE_INV_SQRT_H);
      }
    }
}

// ---------------- K3: fused per-batch attention -------------------------------------------
// LDS 80,064B -> 2 blocks/CU (was 148KB -> 1). Single rm copy of other; GEMM1 = MFMA
// (A=T, B=other, both K-contiguous); GEMM2 = VALU fp32 from rm layout (0.13 GF/block,
// hidden under HBM stream). Probs replicated 4x (stride 1056B) for conflict-free preload.
__global__ __launch_bounds__(256) void k_attn(const float* __restrict__ other,
                                              const unsigned short* __restrict__ T,
                                              unsigned short* __restrict__ wbuf)
{
  __shared__ unsigned short oth[64 * 512];   // [n][kf] bf16, granule-XOR swizzled (64KB)
  __shared__ unsigned short t_lds[8 * 512];  // [h][kf] bf16, swizzled (8KB)
  __shared__ float s_lds[8 * 66];            // scores, padded
  __shared__ char a_raw[4 * 1056];           // 4 replicas of probs [8][64] bf16
  const int b = blockIdx.x;
  const int t = threadIdx.x, l = t & 63, w = t >> 6;

  // stage T rows (8 x 512), swizzle granule = kf>>3 XOR row
  {
    int row = t >> 5;                 // 0..7
    int col0 = (t & 31) * 16;
    const unsigned short* gp = T + (size_t)b * 4096 + row * 512 + col0;
#pragma unroll
    for (int i = 0; i < 2; i++) {
      u32x4 v = *(const u32x4*)(gp + i * 8);
      int gr = (col0 >> 3) + i;
      *(u32x4*)((char*)t_lds + row * 1024 + ((gr ^ row) << 4)) = v;
    }
  }
  // stage other: fp32 -> bf16, rm swizzled; b64 writes are conflict-free
  {
    int n = t >> 2;
    int nx = n & 7;
    const f32x4* gp = (const f32x4*)(other + (size_t)b * 32768 + (size_t)n * 512);
#pragma unroll
    for (int j0 = 0; j0 < 32; j0 += 8) {
      f32x4 v[8];
#pragma unroll
      for (int jj = 0; jj < 8; jj++) v[jj] = gp[(t & 3) + (j0 + jj) * 4];
#pragma unroll
      for (int jj = 0; jj < 8; jj++) {
        int kf0 = (t & 3) * 4 + (j0 + jj) * 16;
        unsigned int lo = (unsigned)f2bf(v[jj][0]) | ((unsigned)f2bf(v[jj][1]) << 16);
        unsigned int hi = (unsigned)f2bf(v[jj][2]) | ((unsigned)f2bf(v[jj][3]) << 16);
        unsigned long long pk = (unsigned long long)lo | ((unsigned long long)hi << 32);
        int g = kf0 >> 3;
        *(unsigned long long*)((char*)oth + n * 1024 + ((g ^ nx) << 4) + (kf0 & 7) * 2) = pk;
      }
    }
  }
  __syncthreads();

  // GEMM1 (MFMA): S[h][n] = sum_kf T[h][kf] * other[n][kf]; wave w owns n in [16w,16w+16)
  {
    f32x4 sacc = {0.f, 0.f, 0.f, 0.f};
    int arow = l & 7;                  // A rows 8..15 duplicate 0..7 (outputs discarded)
    int bn = w * 16 + (l & 15);
    int bx = bn & 7;
#pragma unroll
    for (int kk = 0; kk < 16; kk++) {
      int gr = kk * 4 + (l >> 4);
      s16x8 af  = *(const s16x8*)((char*)t_lds + arow * 1024 + ((gr ^ arow) << 4));
      s16x8 bfv = *(const s16x8*)((char*)oth + bn * 1024 + ((gr ^ bx) << 4));
      sacc = __builtin_amdgcn_mfma_f32_16x16x32_bf16(af, bfv, sacc, 0, 0, 0);
    }
    int hbase = (l >> 4) * 4;
    if (hbase < 8) {
#pragma unroll
      for (int rg = 0; rg < 4; rg++) s_lds[(hbase + rg) * 66 + w * 16 + (l & 15)] = sacc[rg];
    }
  }
  __syncthreads();

  // softmax over n=64 per head; wave w handles heads 2w,2w+1; write 4 prob replicas
#pragma unroll
  for (int hh = 0; hh < 2; hh++) {
    int h = w * 2 + hh;
    float v = s_lds[h * 66 + l];
    float mx = v;
#pragma unroll
    for (int off = 32; off > 0; off >>= 1) mx = fmaxf(mx, __shfl_xor(mx, off));
    float p = __expf(v - mx);
    float sm = p;
#pragma unroll
    for (int off = 32; off > 0; off >>= 1) sm += __shfl_xor(sm, off);
    unsigned short ab = f2bf(p / sm);
#pragma unroll
    for (int rep = 0; rep < 4; rep++)
      *(unsigned short*)(a_raw + rep * 1056 + h * 128 + l * 2) = ab;
  }
  __syncthreads();

  // GEMM2 (VALU): w[h][kf] = sum_n a[h][n]*other[n][kf]
  // wave w owns kf in [128w,128w+128); lane group g = l>>4 owns heads {2g,2g+1};
  // lane owns 8 kf. oth reads broadcast across the 4 groups (same address).
  {
    int g = l >> 4;
    int klane = l & 15;
    int kf0 = w * 128 + klane * 8;
    const char* abase = a_raw + g * 1056;
    s16x8 a0[8], a1[8];
#pragma unroll
    for (int r = 0; r < 8; r++) {
      a0[r] = *(const s16x8*)(abase + (2 * g) * 128 + r * 16);
      a1[r] = *(const s16x8*)(abase + (2 * g + 1) * 128 + r * 16);
    }
    float acc0[8], acc1[8];
#pragma unroll
    for (int q = 0; q < 8; q++) { acc0[q] = 0.f; acc1[q] = 0.f; }
    const char* obase = (const char*)oth;
    int gsl = w * 16 + klane;   // granule index of kf0
#pragma unroll
    for (int r = 0; r < 8; r++) {
#pragma unroll
      for (int jj = 0; jj < 8; jj++) {
        int n = r * 8 + jj;
        float av0 = bf2f((unsigned short)a0[r][jj]);
        float av1 = bf2f((unsigned short)a1[r][jj]);
        s16x8 o = *(const s16x8*)(obase + n * 1024 + ((gsl ^ (n & 7)) << 4));
#pragma unroll
        for (int q = 0; q < 8; q++) {
          float f = bf2f((unsigned short)o[q]);
          acc0[q] += av0 * f;
          acc1[q] += av1 * f;
        }
      }
    }
    int h0 = 2 * g, h1 = h0 + 1;
    u32x4 p0, p1;
#pragma unroll
    for (int q = 0; q < 4; q++) {
      p0[q] = (unsigned)f2bf(acc0[2 * q]) | ((unsigned)f2bf(acc0[2 * q + 1]) << 16);
      p1[q] = (unsigned)f2bf(acc1[2 * q]) | ((unsigned)f2bf(acc1[2 * q + 1]) << 16);
    }
    *(u32x4*)(wbuf + ((size_t)b * 8 + h0) * 512 + kf0) = p0;
    *(u32x4*)(wbuf + ((size_t)b * 8 + h1) * 512 + kf0) = p1;
  }
}

// ---------------- K4: c[b][h*128+d] = sum_k w[b][h][k]*Wv[h][k][d]  (bf16) ---------------
__global__ __launch_bounds__(256) void k_c(const unsigned short* __restrict__ wbuf,
                                           const unsigned short* __restrict__ wvt,
                                           unsigned short* __restrict__ cbuf)
{
  __shared__ unsigned short As[128 * 64], Bs[128 * 64];
  int bid = blockIdx.x;
  int bm = bid >> 3, h = bid & 7;
  f32x4 acc[4][4]; f32x4 z = {0.f, 0.f, 0.f, 0.f};
#pragma unroll
  for (int i = 0; i < 4; i++) for (int j = 0; j < 4; j++) acc[i][j] = z;
  gemm_core(wbuf + ((size_t)bm * 128 * 8 + h) * 512, 4096, wvt + h * 65536, 512, 8, As, Bs, acc);
  store_bf16_tile(cbuf + (size_t)bm * 128 * 1024 + h * 128, 1024, acc);
}

// ---------------- K5: LN + ReLU + out = cn @ Wo  (fp32 out) ------------------------------
__global__ __launch_bounds__(256) void k_out(const unsigned short* __restrict__ cbuf,
                                             const float* __restrict__ gamma,
                                             const float* __restrict__ beta,
                                             const unsigned short* __restrict__ wot,
                                             float* __restrict__ out)
{
  __shared__ unsigned short As[32 * 1024];
  __shared__ unsigned short Bs[128 * 64];
  int bid = blockIdx.x;
  int bm = bid >> 2, bn = bid & 3;
  const int t = threadIdx.x, lane = t & 63, w = t >> 6;
  {
    int r = t >> 3;
    const unsigned short* g = cbuf + (size_t)(bm * 32 + r) * 1024;
#pragma unroll
    for (int q = 0; q < 16; q++) {
      int u = (t & 7) + q * 8;
      u32x4 v = *(const u32x4*)(g + u * 8);
      ((u32x4*)(As + r * 1024))[u ^ (r & 7)] = v;
    }
  }
  float gv[16], bv[16];
#pragma unroll
  for (int si = 0; si < 2; si++)
#pragma unroll
    for (int j = 0; j < 8; j++) {
      int k = (lane + si * 64) * 8 + j;
      gv[si * 8 + j] = gamma[k];
      bv[si * 8 + j] = beta[k];
    }
  __syncthreads();
  for (int rr = 0; rr < 8; rr++) {
    int r = w * 8 + rr;
    float vals[16]; float sum = 0.f, sq = 0.f;
#pragma unroll
    for (int si = 0; si < 2; si++) {
      int s = lane + si * 64;
      s16x8 pv = *(const s16x8*)(As + r * 1024 + ((s ^ (r & 7)) << 3));
#pragma unroll
      for (int j = 0; j < 8; j++) { float f = bf2f((unsigned short)pv[j]); vals[si * 8 + j] = f; sum += f; sq += f * f; }
    }
#pragma unroll
    for (int off = 32; off > 0; off >>= 1) { sum += __shfl_xor(sum, off); sq += __shfl_xor(sq, off); }
    float mu = sum * (1.f / 1024.f);
    float var = sq * (1.f / 1024.f) - mu * mu;
    float rs = rsqrtf(var + 1e-5f);
#pragma unroll
    for (int si = 0; si < 2; si++) {
      int s = lane + si * 64;
      unsigned short o[8];
#pragma unroll
      for (int j = 0; j < 8; j++) {
        float f = (vals[si * 8 + j] - mu) * rs * gv[si * 8 + j] + bv[si * 8 + j];
        o[j] = f2bf(fmaxf(f, 0.f));
      }
      u32x4 pk;
      pk[0] = (unsigned)o[0] | ((unsigned)o[1] << 16);
      pk[1] = (unsigned)o[2] | ((unsigned)o[3] << 16);
      pk[2] = (unsigned)o[4] | ((unsigned)o[5] << 16);
      pk[3] = (unsigned)o[6] | ((unsigned)o[7] << 16);
      ((u32x4*)(As + r * 1024))[s ^ (r & 7)] = pk;
    }
  }
  const int wm = w >> 1, wn = w & 1;
  f32x4 acc[4]; f32x4 z = {0.f, 0.f, 0.f, 0.f};
#pragma unroll
  for (int j = 0; j < 4; j++) acc[j] = z;
  const unsigned short* Bg = wot + (size_t)bn * 128 * 1024;
  const int rB = t >> 1, u0 = (t & 1) * 4;
  for (int kk = 0; kk < 16; kk++) {
    __syncthreads();
#pragma unroll
    for (int q = 0; q < 4; q++) {
      u32x4 vb = *(const u32x4*)(Bg + (size_t)rB * 1024 + kk * 64 + (u0 + q) * 8);
      ((u32x4*)(Bs + rB * 64))[(u0 + q) ^ (rB & 7)] = vb;
    }
    __syncthreads();
#pragma unroll
    for (int ks = 0; ks < 2; ks++) {
      int ra = wm * 16 + (lane & 15);
      int sa = kk * 8 + ks * 4 + (lane >> 4);
      s16x8 af = *(const s16x8*)(As + ra * 1024 + ((sa ^ (ra & 7)) << 3));
#pragma unroll
      for (int j = 0; j < 4; j++) {
        int rb = wn * 64 + j * 16 + (lane & 15);
        int sb = ks * 4 + (lane >> 4);
        s16x8 bfv = *(const s16x8*)(Bs + rb * 64 + ((sb ^ (rb & 7)) << 3));
        acc[j] = __builtin_amdgcn_mfma_f32_16x16x32_bf16(af, bfv, acc[j], 0, 0, 0);
      }
    }
  }
#pragma unroll
  for (int j = 0; j < 4; j++) {
    int col = bn * 128 + wn * 64 + j * 16 + (lane & 15);
#pragma unroll
    for (int rg = 0; rg < 4; rg++) {
      int row = bm * 32 + wm * 16 + (lane >> 4) * 4 + rg;
      out[(size_t)row * 512 + col] = acc[j][rg];
    }
  }
}

// -----------------------------------------------------------------------------------------
extern "C" void kernel_launch(void* const* d_in, const int* in_sizes, int n_in,
                              void* d_out, int out_size, void* d_ws, size_t ws_size,
                              hipStream_t stream)
{
  (void)in_sizes; (void)n_in; (void)out_size;
  const float* me    = (const float*)d_in[0];
  const float* other = (const float*)d_in[1];
  const float* Wq    = (const float*)d_in[2];
  const float* bq    = (const float*)d_in[3];
  const float* Wk    = (const float*)d_in[4];
  const float* Wv    = (const float*)d_in[5];
  const float* gamma = (const float*)d_in[6];
  const float* beta  = (const float*)d_in[7];
  const float* Wo    = (const float*)d_in[8];
  float* out = (float*)d_out;
  char* ws = (char*)d_ws;

  unsigned short* me_b  = (unsigned short*)(ws + 0);          //  2 MB
  unsigned short* wq_b  = (unsigned short*)(ws + 2097152);    //  1 MB
  unsigned short* wk_b  = (unsigned short*)(ws + 3145728);    //  1 MB
  unsigned short* wvt_b = (unsigned short*)(ws + 4194304);    //  1 MB
  unsigned short* wot_b = (unsigned short*)(ws + 5242880);    //  1 MB
  float*          rbuf  = (float*)(ws + 6291456);             // 16 KB
  unsigned short* mt_b  = (unsigned short*)(ws + 6307840);    //  4 MB
  unsigned short* T_b   = (unsigned short*)(ws + 10502144);   // 16 MB
  unsigned short* w_b   = (unsigned short*)(ws + 27279360);   // 16 MB
  unsigned short* c_b   = (unsigned short*)(ws + 44056576);   //  4 MB
  if (ws_size < 48250880) return;

  k_conv<<<dim3(1040), dim3(256), 0, stream>>>(me, Wq, Wk, Wv, Wo, bq,
                                               me_b, wq_b, wk_b, wvt_b, wot_b, rbuf);
  k_mt  <<<dim3(128),  dim3(256), 0, stream>>>(wk_b, wq_b, mt_b);
  k_t   <<<dim3(512),  dim3(256), 0, stream>>>(me_b, mt_b, rbuf, T_b);
  k_attn<<<dim3(2048), dim3(256), 0, stream>>>(other, T_b, w_b);
  k_c   <<<dim3(128),  dim3(256), 0, stream>>>(w_b, wvt_b, c_b);
  k_out <<<dim3(256),  dim3(256), 0, stream>>>(c_b, gamma, beta, wot_b, out);
}

// Round 3
// 129.894 us; speedup vs baseline: 1.1346x; 1.0529x over previous
//
#include <hip/hip_runtime.h>
#include <math.h>

typedef __attribute__((ext_vector_type(4))) float f32x4;
typedef __attribute__((ext_vector_type(4))) unsigned int u32x4;
typedef __attribute__((ext_vector_type(8))) short s16x8;

#define SCALE_INV_SQRT_H 0.08838834764831845f  /* 1/sqrt(128) */

__device__ __forceinline__ unsigned short f2bf(float x){
  unsigned int u = __builtin_bit_cast(unsigned int, x);
  u += 0x7fffu + ((u >> 16) & 1u);
  return (unsigned short)(u >> 16);
}
__device__ __forceinline__ float bf2f(unsigned short s){
  unsigned int u = ((unsigned int)s) << 16;
  return __builtin_bit_cast(float, u);
}

// ---------------- shared 128x128-tile NT GEMM core (A,B both K-contiguous bf16) ---------
__device__ __forceinline__ void gemm_core(
    const unsigned short* __restrict__ Ag, int lda,
    const unsigned short* __restrict__ Bg, int ldb,
    int ksteps, unsigned short* As, unsigned short* Bs, f32x4 acc[4][4])
{
  const int t = threadIdx.x, lane = t & 63, w = t >> 6;
  const int m0 = (w >> 1) * 64, n0 = (w & 1) * 64;
  const int r = t >> 1, u0 = (t & 1) * 4;
  for (int kk = 0; kk < ksteps; kk++) {
    __syncthreads();
    const unsigned short* ga = Ag + (size_t)r * lda + kk * 64;
    const unsigned short* gb = Bg + (size_t)r * ldb + kk * 64;
#pragma unroll
    for (int q = 0; q < 4; q++) {
      u32x4 va = *(const u32x4*)(ga + (u0 + q) * 8);
      u32x4 vb = *(const u32x4*)(gb + (u0 + q) * 8);
      ((u32x4*)(As + r * 64))[(u0 + q) ^ (r & 7)] = va;
      ((u32x4*)(Bs + r * 64))[(u0 + q) ^ (r & 7)] = vb;
    }
    __syncthreads();
    s16x8 af[4][2], bfr[4][2];
#pragma unroll
    for (int i = 0; i < 4; i++) {
#pragma unroll
      for (int ks = 0; ks < 2; ks++) {
        int ra = m0 + i * 16 + (lane & 15);
        int sa = ks * 4 + (lane >> 4);
        af[i][ks] = *(const s16x8*)(As + ra * 64 + ((sa ^ (ra & 7)) << 3));
        int rb = n0 + i * 16 + (lane & 15);
        bfr[i][ks] = *(const s16x8*)(Bs + rb * 64 + ((sa ^ (rb & 7)) << 3));
      }
    }
#pragma unroll
    for (int ks = 0; ks < 2; ks++)
#pragma unroll
      for (int i = 0; i < 4; i++)
#pragma unroll
        for (int j = 0; j < 4; j++)
          acc[i][j] = __builtin_amdgcn_mfma_f32_16x16x32_bf16(af[i][ks], bfr[j][ks], acc[i][j], 0, 0, 0);
  }
}

__device__ __forceinline__ void store_bf16_tile(unsigned short* __restrict__ C, int ldc, f32x4 acc[4][4]){
  const int t = threadIdx.x, lane = t & 63, w = t >> 6;
  const int m0 = (w >> 1) * 64, n0 = (w & 1) * 64;
#pragma unroll
  for (int i = 0; i < 4; i++)
#pragma unroll
    for (int j = 0; j < 4; j++) {
      int col = n0 + j * 16 + (lane & 15);
#pragma unroll
      for (int rg = 0; rg < 4; rg++) {
        int row = m0 + i * 16 + (lane >> 4) * 4 + rg;
        C[(size_t)row * ldc + col] = f2bf(acc[i][j][rg]);
      }
    }
}

// ---------------- 64x64 fp32->bf16 LDS-tile transpose -----------------------------------
// src [R][C] fp32 (lda), dst [C][R] bf16 (ldb); tile origin (r0,c0). 256 threads.
__device__ __forceinline__ void transpose_tile(const float* __restrict__ src, int lda,
                                               unsigned short* __restrict__ dst, int ldb,
                                               int r0, int c0, unsigned short (*tile)[72])
{
  const int t = threadIdx.x;
  const int cc = (t & 15) * 4, rr = t >> 4;
#pragma unroll
  for (int j = 0; j < 4; j++) {
    int r = rr + j * 16;
    f32x4 v = *(const f32x4*)(src + (size_t)(r0 + r) * lda + c0 + cc);
#pragma unroll
    for (int q = 0; q < 4; q++) tile[r][cc + q] = f2bf(v[q]);
  }
  __syncthreads();
  const int c = t >> 2, rb = (t & 3) * 16;
  unsigned short o[16];
#pragma unroll
  for (int q = 0; q < 16; q++) o[q] = tile[rb + q][c];
  u32x4 p0, p1;
#pragma unroll
  for (int q = 0; q < 4; q++) {
    p0[q] = (unsigned)o[2 * q]     | ((unsigned)o[2 * q + 1] << 16);
    p1[q] = (unsigned)o[2 * q + 8] | ((unsigned)o[2 * q + 9] << 16);
  }
  unsigned short* dp = dst + (size_t)(c0 + c) * ldb + r0 + rb;
  *(u32x4*)dp = p0;
  *(u32x4*)(dp + 8) = p1;
}

// ---------------- K0: convert me/Wk + transpose Wq/Wv/Wo (all fp32 -> bf16) -------------
// blocks 0..255: convert me (1M) + Wk (512K) elems, vectorized
// blocks 256..383: Wq[h][i][d] -> wqt[h][d][i]
// blocks 384..511: Wv[h][k][d] -> wvt[h][d][k]
// blocks 512..639: Wo[k][n]    -> wot[n][k]
__global__ __launch_bounds__(256) void k_conv(
  const float* __restrict__ me, const float* __restrict__ Wq, const float* __restrict__ Wk,
  const float* __restrict__ Wv, const float* __restrict__ Wo,
  unsigned short* __restrict__ me_b, unsigned short* __restrict__ wk_b,
  unsigned short* __restrict__ wqt, unsigned short* __restrict__ wvt,
  unsigned short* __restrict__ wot)
{
  __shared__ unsigned short tile[64][72];
  const int bid = blockIdx.x, t = threadIdx.x;
  if (bid < 256) {
    // 393216 f32x4 quads: me first 262144, then Wk 131072
    for (int v = bid * 256 + t; v < 393216; v += 256 * 256) {
      const float* sp; unsigned short* dp;
      if (v < 262144) { sp = me + 4 * (size_t)v; dp = me_b + 4 * (size_t)v; }
      else { int i = v - 262144; sp = Wk + 4 * (size_t)i; dp = wk_b + 4 * (size_t)i; }
      f32x4 x = *(const f32x4*)sp;
      unsigned long long pk = (unsigned long long)((unsigned)f2bf(x[0]) | ((unsigned)f2bf(x[1]) << 16))
                            | (((unsigned long long)((unsigned)f2bf(x[2]) | ((unsigned)f2bf(x[3]) << 16))) << 32);
      *(unsigned long long*)dp = pk;
    }
    return;
  }
  if (bid < 384) {            // Wq: per head [512][128] -> [128][512]
    int idx = bid - 256, h = idx >> 4, tl = idx & 15;
    transpose_tile(Wq + (size_t)h * 65536, 128, wqt + (size_t)h * 65536, 512,
                   (tl >> 1) * 64, (tl & 1) * 64, tile);
  } else if (bid < 512) {     // Wv: same geometry
    int idx = bid - 384, h = idx >> 4, tl = idx & 15;
    transpose_tile(Wv + (size_t)h * 65536, 128, wvt + (size_t)h * 65536, 512,
                   (tl >> 1) * 64, (tl & 1) * 64, tile);
  } else {                    // Wo: [1024][512] -> [512][1024]
    int idx = bid - 512;
    transpose_tile(Wo, 512, wot, 1024, (idx >> 3) * 64, (idx & 7) * 64, tile);
  }
}

// ---------------- K1: q[b][h*128+d] = me[b]·Wq[h][:,d] + bq[h*128+d]  (bf16) ------------
__global__ __launch_bounds__(256) void k_q(const unsigned short* __restrict__ me_b,
                                           const unsigned short* __restrict__ wqt,
                                           const float* __restrict__ bq,
                                           unsigned short* __restrict__ q_b)
{
  __shared__ unsigned short As[128 * 64], Bs[128 * 64];
  int bid = blockIdx.x;                 // 16 bm x 8 bn
  int bm = bid >> 3, bn = bid & 7;
  f32x4 acc[4][4]; f32x4 z = {0.f, 0.f, 0.f, 0.f};
#pragma unroll
  for (int i = 0; i < 4; i++) for (int j = 0; j < 4; j++) acc[i][j] = z;
  gemm_core(me_b + (size_t)bm * 128 * 512, 512, wqt + (size_t)bn * 65536, 512, 8, As, Bs, acc);
  const int t = threadIdx.x, lane = t & 63, w = t >> 6;
  const int m0 = (w >> 1) * 64, n0 = (w & 1) * 64;
#pragma unroll
  for (int i = 0; i < 4; i++)
#pragma unroll
    for (int j = 0; j < 4; j++) {
      int col = bn * 128 + n0 + j * 16 + (lane & 15);
      float bqv = bq[col];
#pragma unroll
      for (int rg = 0; rg < 4; rg++) {
        int row = bm * 128 + m0 + i * 16 + (lane >> 4) * 4 + rg;
        q_b[(size_t)row * 1024 + col] = f2bf(acc[i][j][rg] + bqv);
      }
    }
}

// ---------------- K2: T[b][h*512+j] = (q[b][h*128:]·Wk[h][j][:]) * scale  (bf16) --------
__global__ __launch_bounds__(256) void k_u(const unsigned short* __restrict__ q_b,
                                           const unsigned short* __restrict__ wk_b,
                                           unsigned short* __restrict__ T)
{
  __shared__ unsigned short As[128 * 64], Bs[128 * 64];
  int bid = blockIdx.x;                 // 8 h x 16 bm x 4 bn
  int h = bid >> 6, bm = (bid >> 2) & 15, bn = bid & 3;
  f32x4 acc[4][4]; f32x4 z = {0.f, 0.f, 0.f, 0.f};
#pragma unroll
  for (int i = 0; i < 4; i++) for (int j = 0; j < 4; j++) acc[i][j] = z;
  gemm_core(q_b + (size_t)bm * 128 * 1024 + h * 128, 1024,
            wk_b + (size_t)h * 65536 + bn * 16384, 128, 2, As, Bs, acc);
  const int t = threadIdx.x, lane = t & 63, w = t >> 6;
  const int m0 = (w >> 1) * 64, n0 = (w & 1) * 64;
#pragma unroll
  for (int i = 0; i < 4; i++)
#pragma unroll
    for (int j = 0; j < 4; j++) {
      int col = h * 512 + bn * 128 + n0 + j * 16 + (lane & 15);
#pragma unroll
      for (int rg = 0; rg < 4; rg++) {
        int row = bm * 128 + m0 + i * 16 + (lane >> 4) * 4 + rg;
        T[(size_t)row * 4096 + col] = f2bf(acc[i][j][rg] * SCALE_INV_SQRT_H);
      }
    }
}

// ---------------- K3: fused per-batch attention -------------------------------------------
__global__ __launch_bounds__(256) void k_attn(const float* __restrict__ other,
                                              const unsigned short* __restrict__ T,
                                              unsigned short* __restrict__ wbuf)
{
  __shared__ unsigned short oth[64 * 512];   // [n][kf] bf16, granule-XOR swizzled (64KB)
  __shared__ unsigned short t_lds[8 * 512];  // [h][kf] bf16, swizzled (8KB)
  __shared__ float s_lds[8 * 66];            // scores, padded
  __shared__ char a_raw[4 * 1056];           // 4 replicas of probs [8][64] bf16
  const int b = blockIdx.x;
  const int t = threadIdx.x, l = t & 63, w = t >> 6;

  // stage T rows (8 x 512), swizzle granule = kf>>3 XOR row
  {
    int row = t >> 5;                 // 0..7
    int col0 = (t & 31) * 16;
    const unsigned short* gp = T + (size_t)b * 4096 + row * 512 + col0;
#pragma unroll
    for (int i = 0; i < 2; i++) {
      u32x4 v = *(const u32x4*)(gp + i * 8);
      int gr = (col0 >> 3) + i;
      *(u32x4*)((char*)t_lds + row * 1024 + ((gr ^ row) << 4)) = v;
    }
  }
  // stage other: fp32 -> bf16, rm swizzled; b64 writes are conflict-free
  {
    int n = t >> 2;
    int nx = n & 7;
    const f32x4* gp = (const f32x4*)(other + (size_t)b * 32768 + (size_t)n * 512);
#pragma unroll
    for (int j0 = 0; j0 < 32; j0 += 8) {
      f32x4 v[8];
#pragma unroll
      for (int jj = 0; jj < 8; jj++) v[jj] = gp[(t & 3) + (j0 + jj) * 4];
#pragma unroll
      for (int jj = 0; jj < 8; jj++) {
        int kf0 = (t & 3) * 4 + (j0 + jj) * 16;
        unsigned int lo = (unsigned)f2bf(v[jj][0]) | ((unsigned)f2bf(v[jj][1]) << 16);
        unsigned int hi = (unsigned)f2bf(v[jj][2]) | ((unsigned)f2bf(v[jj][3]) << 16);
        unsigned long long pk = (unsigned long long)lo | ((unsigned long long)hi << 32);
        int g = kf0 >> 3;
        *(unsigned long long*)((char*)oth + n * 1024 + ((g ^ nx) << 4) + (kf0 & 7) * 2) = pk;
      }
    }
  }
  __syncthreads();

  // GEMM1 (MFMA): S[h][n] = sum_kf T[h][kf] * other[n][kf]; wave w owns n in [16w,16w+16)
  {
    f32x4 sacc = {0.f, 0.f, 0.f, 0.f};
    int arow = l & 7;                  // A rows 8..15 duplicate 0..7 (outputs discarded)
    int bn = w * 16 + (l & 15);
    int bx = bn & 7;
#pragma unroll
    for (int kk = 0; kk < 16; kk++) {
      int gr = kk * 4 + (l >> 4);
      s16x8 af  = *(const s16x8*)((char*)t_lds + arow * 1024 + ((gr ^ arow) << 4));
      s16x8 bfv = *(const s16x8*)((char*)oth + bn * 1024 + ((gr ^ bx) << 4));
      sacc = __builtin_amdgcn_mfma_f32_16x16x32_bf16(af, bfv, sacc, 0, 0, 0);
    }
    int hbase = (l >> 4) * 4;
    if (hbase < 8) {
#pragma unroll
      for (int rg = 0; rg < 4; rg++) s_lds[(hbase + rg) * 66 + w * 16 + (l & 15)] = sacc[rg];
    }
  }
  __syncthreads();

  // softmax over n=64 per head; wave w handles heads 2w,2w+1; write 4 prob replicas
#pragma unroll
  for (int hh = 0; hh < 2; hh++) {
    int h = w * 2 + hh;
    float v = s_lds[h * 66 + l];
    float mx = v;
#pragma unroll
    for (int off = 32; off > 0; off >>= 1) mx = fmaxf(mx, __shfl_xor(mx, off));
    float p = __expf(v - mx);
    float sm = p;
#pragma unroll
    for (int off = 32; off > 0; off >>= 1) sm += __shfl_xor(sm, off);
    unsigned short ab = f2bf(p / sm);
#pragma unroll
    for (int rep = 0; rep < 4; rep++)
      *(unsigned short*)(a_raw + rep * 1056 + h * 128 + l * 2) = ab;
  }
  __syncthreads();

  // GEMM2 (VALU): w[h][kf] = sum_n a[h][n]*other[n][kf]
  {
    int g = l >> 4;
    int klane = l & 15;
    int kf0 = w * 128 + klane * 8;
    const char* abase = a_raw + g * 1056;
    s16x8 a0[8], a1[8];
#pragma unroll
    for (int r = 0; r < 8; r++) {
      a0[r] = *(const s16x8*)(abase + (2 * g) * 128 + r * 16);
      a1[r] = *(const s16x8*)(abase + (2 * g + 1) * 128 + r * 16);
    }
    float acc0[8], acc1[8];
#pragma unroll
    for (int q = 0; q < 8; q++) { acc0[q] = 0.f; acc1[q] = 0.f; }
    const char* obase = (const char*)oth;
    int gsl = w * 16 + klane;   // granule index of kf0
#pragma unroll
    for (int r = 0; r < 8; r++) {
#pragma unroll
      for (int jj = 0; jj < 8; jj++) {
        int n = r * 8 + jj;
        float av0 = bf2f((unsigned short)a0[r][jj]);
        float av1 = bf2f((unsigned short)a1[r][jj]);
        s16x8 o = *(const s16x8*)(obase + n * 1024 + ((gsl ^ (n & 7)) << 4));
#pragma unroll
        for (int q = 0; q < 8; q++) {
          float f = bf2f((unsigned short)o[q]);
          acc0[q] += av0 * f;
          acc1[q] += av1 * f;
        }
      }
    }
    int h0 = 2 * g, h1 = h0 + 1;
    u32x4 p0, p1;
#pragma unroll
    for (int q = 0; q < 4; q++) {
      p0[q] = (unsigned)f2bf(acc0[2 * q]) | ((unsigned)f2bf(acc0[2 * q + 1]) << 16);
      p1[q] = (unsigned)f2bf(acc1[2 * q]) | ((unsigned)f2bf(acc1[2 * q + 1]) << 16);
    }
    *(u32x4*)(wbuf + ((size_t)b * 8 + h0) * 512 + kf0) = p0;
    *(u32x4*)(wbuf + ((size_t)b * 8 + h1) * 512 + kf0) = p1;
  }
}

// ---------------- K4: c[b][h*128+d] = sum_k w[b][h][k]*Wv[h][k][d]  (bf16) ---------------
__global__ __launch_bounds__(256) void k_c(const unsigned short* __restrict__ wbuf,
                                           const unsigned short* __restrict__ wvt,
                                           unsigned short* __restrict__ cbuf)
{
  __shared__ unsigned short As[128 * 64], Bs[128 * 64];
  int bid = blockIdx.x;
  int bm = bid >> 3, h = bid & 7;
  f32x4 acc[4][4]; f32x4 z = {0.f, 0.f, 0.f, 0.f};
#pragma unroll
  for (int i = 0; i < 4; i++) for (int j = 0; j < 4; j++) acc[i][j] = z;
  gemm_core(wbuf + ((size_t)bm * 128 * 8 + h) * 512, 4096, wvt + (size_t)h * 65536, 512, 8, As, Bs, acc);
  store_bf16_tile(cbuf + (size_t)bm * 128 * 1024 + h * 128, 1024, acc);
}

// ---------------- K5: LN + ReLU + out = cn @ Wo  (fp32 out) ------------------------------
__global__ __launch_bounds__(256) void k_out(const unsigned short* __restrict__ cbuf,
                                             const float* __restrict__ gamma,
                                             const float* __restrict__ beta,
                                             const unsigned short* __restrict__ wot,
                                             float* __restrict__ out)
{
  __shared__ unsigned short As[32 * 1024];
  __shared__ unsigned short Bs[128 * 64];
  int bid = blockIdx.x;
  int bm = bid >> 2, bn = bid & 3;
  const int t = threadIdx.x, lane = t & 63, w = t >> 6;
  {
    int r = t >> 3;
    const unsigned short* g = cbuf + (size_t)(bm * 32 + r) * 1024;
#pragma unroll
    for (int q = 0; q < 16; q++) {
      int u = (t & 7) + q * 8;
      u32x4 v = *(const u32x4*)(g + u * 8);
      ((u32x4*)(As + r * 1024))[u ^ (r & 7)] = v;
    }
  }
  float gv[16], bv[16];
#pragma unroll
  for (int si = 0; si < 2; si++)
#pragma unroll
    for (int j = 0; j < 8; j++) {
      int k = (lane + si * 64) * 8 + j;
      gv[si * 8 + j] = gamma[k];
      bv[si * 8 + j] = beta[k];
    }
  __syncthreads();
  for (int rr = 0; rr < 8; rr++) {
    int r = w * 8 + rr;
    float vals[16]; float sum = 0.f, sq = 0.f;
#pragma unroll
    for (int si = 0; si < 2; si++) {
      int s = lane + si * 64;
      s16x8 pv = *(const s16x8*)(As + r * 1024 + ((s ^ (r & 7)) << 3));
#pragma unroll
      for (int j = 0; j < 8; j++) { float f = bf2f((unsigned short)pv[j]); vals[si * 8 + j] = f; sum += f; sq += f * f; }
    }
#pragma unroll
    for (int off = 32; off > 0; off >>= 1) { sum += __shfl_xor(sum, off); sq += __shfl_xor(sq, off); }
    float mu = sum * (1.f / 1024.f);
    float var = sq * (1.f / 1024.f) - mu * mu;
    float rs = rsqrtf(var + 1e-5f);
#pragma unroll
    for (int si = 0; si < 2; si++) {
      int s = lane + si * 64;
      unsigned short o[8];
#pragma unroll
      for (int j = 0; j < 8; j++) {
        float f = (vals[si * 8 + j] - mu) * rs * gv[si * 8 + j] + bv[si * 8 + j];
        o[j] = f2bf(fmaxf(f, 0.f));
      }
      u32x4 pk;
      pk[0] = (unsigned)o[0] | ((unsigned)o[1] << 16);
      pk[1] = (unsigned)o[2] | ((unsigned)o[3] << 16);
      pk[2] = (unsigned)o[4] | ((unsigned)o[5] << 16);
      pk[3] = (unsigned)o[6] | ((unsigned)o[7] << 16);
      ((u32x4*)(As + r * 1024))[s ^ (r & 7)] = pk;
    }
  }
  const int wm = w >> 1, wn = w & 1;
  f32x4 acc[4]; f32x4 z = {0.f, 0.f, 0.f, 0.f};
#pragma unroll
  for (int j = 0; j < 4; j++) acc[j] = z;
  const unsigned short* Bg = wot + (size_t)bn * 128 * 1024;
  const int rB = t >> 1, u0 = (t & 1) * 4;
  for (int kk = 0; kk < 16; kk++) {
    __syncthreads();
#pragma unroll
    for (int q = 0; q < 4; q++) {
      u32x4 vb = *(const u32x4*)(Bg + (size_t)rB * 1024 + kk * 64 + (u0 + q) * 8);
      ((u32x4*)(Bs + rB * 64))[(u0 + q) ^ (rB & 7)] = vb;
    }
    __syncthreads();
#pragma unroll
    for (int ks = 0; ks < 2; ks++) {
      int ra = wm * 16 + (lane & 15);
      int sa = kk * 8 + ks * 4 + (lane >> 4);
      s16x8 af = *(const s16x8*)(As + ra * 1024 + ((sa ^ (ra & 7)) << 3));
#pragma unroll
      for (int j = 0; j < 4; j++) {
        int rb = wn * 64 + j * 16 + (lane & 15);
        int sb = ks * 4 + (lane >> 4);
        s16x8 bfv = *(const s16x8*)(Bs + rb * 64 + ((sb ^ (rb & 7)) << 3));
        acc[j] = __builtin_amdgcn_mfma_f32_16x16x32_bf16(af, bfv, acc[j], 0, 0, 0);
      }
    }
  }
#pragma unroll
  for (int j = 0; j < 4; j++) {
    int col = bn * 128 + wn * 64 + j * 16 + (lane & 15);
#pragma unroll
    for (int rg = 0; rg < 4; rg++) {
      int row = bm * 32 + wm * 16 + (lane >> 4) * 4 + rg;
      out[(size_t)row * 512 + col] = acc[j][rg];
    }
  }
}

// -----------------------------------------------------------------------------------------
extern "C" void kernel_launch(void* const* d_in, const int* in_sizes, int n_in,
                              void* d_out, int out_size, void* d_ws, size_t ws_size,
                              hipStream_t stream)
{
  (void)in_sizes; (void)n_in; (void)out_size;
  const float* me    = (const float*)d_in[0];
  const float* other = (const float*)d_in[1];
  const float* Wq    = (const float*)d_in[2];
  const float* bq    = (const float*)d_in[3];
  const float* Wk    = (const float*)d_in[4];
  const float* Wv    = (const float*)d_in[5];
  const float* gamma = (const float*)d_in[6];
  const float* beta  = (const float*)d_in[7];
  const float* Wo    = (const float*)d_in[8];
  float* out = (float*)d_out;
  char* ws = (char*)d_ws;

  unsigned short* me_b = (unsigned short*)(ws + 0);          //  2 MB  me bf16
  unsigned short* wk_b = (unsigned short*)(ws + 2097152);    //  1 MB  Wk bf16 (as stored)
  unsigned short* wqt  = (unsigned short*)(ws + 3145728);    //  1 MB  Wq^T per head
  unsigned short* wvt  = (unsigned short*)(ws + 4194304);    //  1 MB  Wv^T per head
  unsigned short* wot  = (unsigned short*)(ws + 5242880);    //  1 MB  Wo^T
  unsigned short* q_b  = (unsigned short*)(ws + 6291456);    //  4 MB  q = me@Wq+bq
  unsigned short* T_b  = (unsigned short*)(ws + 10485760);   // 16 MB  u = q@Wk^T (scaled)
  unsigned short* w_b  = (unsigned short*)(ws + 27262976);   // 16 MB  w = a@other
  unsigned short* c_b  = (unsigned short*)(ws + 44040192);   //  4 MB  c = w@Wv
  if (ws_size < 48234496) return;

  k_conv<<<dim3(640),  dim3(256), 0, stream>>>(me, Wq, Wk, Wv, Wo, me_b, wk_b, wqt, wvt, wot);
  k_q   <<<dim3(128),  dim3(256), 0, stream>>>(me_b, wqt, bq, q_b);
  k_u   <<<dim3(512),  dim3(256), 0, stream>>>(q_b, wk_b, T_b);
  k_attn<<<dim3(2048), dim3(256), 0, stream>>>(other, T_b, w_b);
  k_c   <<<dim3(128),  dim3(256), 0, stream>>>(w_b, wvt, c_b);
  k_out <<<dim3(256),  dim3(256), 0, stream>>>(c_b, gamma, beta, wot, out);
}